// Round 10
// baseline (197.526 us; speedup 1.0000x reference)
//
#include <hip/hip_runtime.h>
#include <hip/hip_bf16.h>
#include <stdint.h>

#define B_ 8
#define N_ 1024
#define C_ 1024
#define H_ 16

static constexpr float SCALE = 0.125f;            // 64^-0.5
static constexpr float LOG2E = 1.4426950408889634f;
static constexpr float SL    = SCALE * LOG2E;     // folded into Wq at cvt time

typedef __attribute__((ext_vector_type(4))) float f32x4;
typedef __attribute__((ext_vector_type(8))) short s16x8;

__device__ __forceinline__ ushort f2bf(float f) {
    union { float f; uint32_t u; } c; c.f = f;
    uint32_t u = c.u;
    return (ushort)((u + 0x7fffu + ((u >> 16) & 1u)) >> 16);
}

// compiler-friendly cast: hipcc fuses pairs into v_cvt_pk_bf16_f32 (m240)
__device__ __forceinline__ ushort f2bfc(float f) {
    union { __hip_bfloat16 h; ushort u; } c;
    c.h = __float2bfloat16(f);
    return c.u;
}

__device__ __forceinline__ void gload_lds16(const void* g, void* l) {
    __builtin_amdgcn_global_load_lds(
        (const __attribute__((address_space(1))) void*)g,
        (__attribute__((address_space(3))) void*)l,
        16, 0, 0);
}
__device__ __forceinline__ void gload_lds4(const void* g, void* l) {
    __builtin_amdgcn_global_load_lds(
        (const __attribute__((address_space(1))) void*)g,
        (__attribute__((address_space(3))) void*)l,
        4, 0, 0);
}

// ---------------- fused fp32 -> bf16 conversion for all three inputs ----------------
__global__ __launch_bounds__(256) void cvt_all(const float* __restrict__ x,
                                               const float* __restrict__ qkv_w,
                                               const float* __restrict__ proj_w,
                                               ushort* __restrict__ xb,
                                               ushort* __restrict__ wqkv,
                                               ushort* __restrict__ wproj) {
    int i = blockIdx.x * 256 + threadIdx.x;
    const float* src;
    ushort* dst;
    float sc = 1.0f;
    if (i < 2097152) {
        src = x; dst = xb;
    } else if (i < 2097152 + 786432) {
        i -= 2097152;
        src = qkv_w; dst = wqkv;
        if (i < 262144) sc = SL;
    } else {
        i -= 2097152 + 786432;
        src = proj_w; dst = wproj;
    }
    float4 v = ((const float4*)src)[i];
    ushort4 o = make_ushort4(f2bf(v.x * sc), f2bf(v.y * sc), f2bf(v.z * sc), f2bf(v.w * sc));
    ((ushort4*)dst)[i] = o;
}

// ---------------- 128x128 m97-structure GEMM: C = A * B^T ----------------
template<int OUT_BF16>
__global__ __launch_bounds__(256) void gemm_bt(const ushort* __restrict__ A,
                                               const ushort* __restrict__ Bw,
                                               void* __restrict__ Cout,
                                               const float* __restrict__ bias,
                                               int M, int Nout, int K) {
    __shared__ ushort Asm[128 * 64];
    __shared__ ushort Bsm[128 * 64];
    const int t = threadIdx.x;
    const int l = t & 63, w = t >> 6;
    const int lq = l & 15, lg = l >> 4;
    const int trow = blockIdx.y * 128, tcol = blockIdx.x * 128;
    const int wrow = (w >> 1) * 64, wcol = (w & 1) * 64;

    f32x4 acc[4][4] = {};

    const int srow0 = t >> 3;
    const int sc8 = (((t & 7) ^ (srow0 & 7)) * 8);
    const size_t abase = (size_t)(trow + srow0) * K + sc8;
    const size_t bbase = (size_t)(tcol + srow0) * K + sc8;

    for (int k0 = 0; k0 < K; k0 += 64) {
#pragma unroll
        for (int i = 0; i < 4; ++i) {
            gload_lds16(A + abase + (size_t)i * 32 * K + k0, &Asm[(i * 256 + w * 64) * 8]);
            gload_lds16(Bw + bbase + (size_t)i * 32 * K + k0, &Bsm[(i * 256 + w * 64) * 8]);
        }
        __syncthreads();
#pragma unroll
        for (int kk = 0; kk < 2; ++kk) {
            s16x8 af[4], bf[4];
#pragma unroll
            for (int m = 0; m < 4; ++m) {
                int row = wrow + m * 16 + lq;
                int ch = (kk * 4 + lg) ^ (row & 7);
                af[m] = *(const s16x8*)&Asm[row * 64 + ch * 8];
            }
#pragma unroll
            for (int n = 0; n < 4; ++n) {
                int row = wcol + n * 16 + lq;
                int ch = (kk * 4 + lg) ^ (row & 7);
                bf[n] = *(const s16x8*)&Bsm[row * 64 + ch * 8];
            }
#pragma unroll
            for (int m = 0; m < 4; ++m)
#pragma unroll
                for (int n = 0; n < 4; ++n)
                    acc[m][n] = __builtin_amdgcn_mfma_f32_16x16x32_bf16(af[m], bf[n], acc[m][n], 0, 0, 0);
        }
        __syncthreads();
    }

#pragma unroll
    for (int m = 0; m < 4; ++m)
#pragma unroll
        for (int n = 0; n < 4; ++n)
#pragma unroll
            for (int r = 0; r < 4; ++r) {
                int row = trow + wrow + m * 16 + lg * 4 + r;
                int col = tcol + wcol + n * 16 + lq;
                if (OUT_BF16) {
                    ((ushort*)Cout)[(size_t)row * Nout + col] = f2bfc(acc[m][n][r]);
                } else {
                    ((float*)Cout)[(size_t)row * Nout + col] = acc[m][n][r] + bias[col];
                }
            }
}

// ---------------- fused flash attention ----------------
// QBLK=256 (8 waves x 32 q-rows, two 16-row subtiles/wave), KVBLK=128 (barriers/loop
// overhead halved vs r9). grid 512 blocks (2/CU). Single-buffer, 2 barriers/tile.
// K: 2 gload_lds16/thread, [128][64] 16B-chunk XOR swizzle (row 64 = row 0 mod 8).
// V: Vlds[64 d][128 slots]; 8 gload_lds4/thread, one 256B d-row per wave-DMA (d=w*8+j),
//    key-permutation + bank-swizzle folded into per-lane SOURCE addresses:
//    lane l -> physical chunk p=l>>2, logical c=p^(d&7), slots s=c*8+(l&3)*2, s+1,
//    key(s) = (2*(s>>5)+((s>>2)&1))*16 + ((s>>3)&3)*4 + (s&3).
// Swapped QK^T: lane owns scores of query q=l&15 (8 key-groups); unnormalized softmax
// (Q pre-scaled by SL; exp2 direct); l_run reduced once at epilogue.
__global__ __launch_bounds__(512, 4) void attn_fwd(const ushort* __restrict__ qk,
                                                   const ushort* __restrict__ vt,
                                                   ushort* __restrict__ attn_out) {
    __shared__ ushort Klds[128 * 64];
    __shared__ ushort Vlds[64 * 128];

    const int t = threadIdx.x, l = t & 63, w = t >> 6;
    const int lq = l & 15, lg = l >> 4;

    // XCD swizzle over 512 blocks: 64 logical/XCD = 16 bh x 4 q-tiles (qt fastest)
    const int serial = blockIdx.x + 4 * blockIdx.y;
    const int logical = (serial & 7) * 64 + (serial >> 3);
    const int qt = logical & 3;
    const int bh = logical >> 2;
    const int b = bh >> 4, h = bh & 15;

    // two q-subtiles per wave: rows qbase and qbase+16
    const int qbase = qt * 256 + w * 32 + lq;
    const size_t qoff0 = (size_t)(b * N_ + qbase) * 2048 + h * 64;
    const size_t qoff1 = qoff0 + (size_t)16 * 2048;
    const s16x8 qa0 = *(const s16x8*)&qk[qoff0 + lg * 8];
    const s16x8 qa1 = *(const s16x8*)&qk[qoff0 + 32 + lg * 8];
    const s16x8 qb0 = *(const s16x8*)&qk[qoff1 + lg * 8];
    const s16x8 qb1 = *(const s16x8*)&qk[qoff1 + 32 + lg * 8];

    float lr0 = 0.f, lr1 = 0.f;
    f32x4 o0[4] = {}, o1[4] = {};

    // K staging: thread t -> rows t>>3 and 64+(t>>3); chunk t&7 pre-swizzled
    const int srow0 = t >> 3;
    const int sc8 = ((t & 7) ^ (srow0 & 7)) * 8;
    const size_t kgbase = (size_t)(b * N_ + srow0) * 2048 + 1024 + h * 64 + sc8;

    // V staging: 8 DMAs x 4B; DMA j covers d-row w*8+j
    const ushort* vptr[8];
#pragma unroll
    for (int j = 0; j < 8; ++j) {
        const int d = w * 8 + j;
        const int c = (l >> 2) ^ (d & 7);
        const int s = c * 8 + (l & 3) * 2;
        const int key = (2 * (s >> 5) + ((s >> 2) & 1)) * 16 + ((s >> 3) & 3) * 4 + (s & 3);
        vptr[j] = vt + (size_t)(h * 64 + d) * (B_ * N_) + b * N_ + key;
    }

    for (int kt = 0; kt < N_ / 128; ++kt) {
        const size_t koff = kgbase + (size_t)kt * 128 * 2048;
        gload_lds16(qk + koff, &Klds[w * 512]);
        gload_lds16(qk + koff + (size_t)64 * 2048, &Klds[4096 + w * 512]);
#pragma unroll
        for (int j = 0; j < 8; ++j)
            gload_lds4(vptr[j] + kt * 128, &Vlds[(w * 8 + j) * 128]);
        __syncthreads();

        f32x4 s0[8], s1[8];
#pragma unroll
        for (int g = 0; g < 8; ++g) {
            int key = g * 16 + lq;
            const s16x8 kf0 = *(const s16x8*)&Klds[key * 64 + ((lg ^ (key & 7)) * 8)];
            const s16x8 kf1 = *(const s16x8*)&Klds[key * 64 + (((4 + lg) ^ (key & 7)) * 8)];
            f32x4 z0 = {}, z1 = {};
            z0    = __builtin_amdgcn_mfma_f32_16x16x32_bf16(kf0, qa0, z0, 0, 0, 0);
            s0[g] = __builtin_amdgcn_mfma_f32_16x16x32_bf16(kf1, qa1, z0, 0, 0, 0);
            z1    = __builtin_amdgcn_mfma_f32_16x16x32_bf16(kf0, qb0, z1, 0, 0, 0);
            s1[g] = __builtin_amdgcn_mfma_f32_16x16x32_bf16(kf1, qb1, z1, 0, 0, 0);
        }

        // exp2 + pack fused per kb; each V-frag read feeds two MFMAs
#pragma unroll
        for (int kb = 0; kb < 4; ++kb) {
            s16x8 pf0, pf1;
#pragma unroll
            for (int i = 0; i < 4; ++i) {
                float a0 = __builtin_amdgcn_exp2f(s0[2 * kb][i]);
                float a1 = __builtin_amdgcn_exp2f(s0[2 * kb + 1][i]);
                float b0 = __builtin_amdgcn_exp2f(s1[2 * kb][i]);
                float b1 = __builtin_amdgcn_exp2f(s1[2 * kb + 1][i]);
                lr0 += a0 + a1;
                lr1 += b0 + b1;
                pf0[i] = (short)f2bfc(a0); pf0[4 + i] = (short)f2bfc(a1);
                pf1[i] = (short)f2bfc(b0); pf1[4 + i] = (short)f2bfc(b1);
            }
#pragma unroll
            for (int ds = 0; ds < 4; ++ds) {
                const s16x8 vf = *(const s16x8*)
                    &Vlds[(ds * 16 + lq) * 128 + (((kb * 4 + lg) ^ (lq & 7)) * 8)];
                o0[ds] = __builtin_amdgcn_mfma_f32_16x16x32_bf16(pf0, vf, o0[ds], 0, 0, 0);
                o1[ds] = __builtin_amdgcn_mfma_f32_16x16x32_bf16(pf1, vf, o1[ds], 0, 0, 0);
            }
        }
        __syncthreads();
    }

    lr0 += __shfl_xor(lr0, 16); lr0 += __shfl_xor(lr0, 32);
    lr1 += __shfl_xor(lr1, 16); lr1 += __shfl_xor(lr1, 32);

#pragma unroll
    for (int r = 0; r < 4; ++r) {
        float rl0 = 1.f / __shfl(lr0, lg * 4 + r);
        float rl1 = 1.f / __shfl(lr1, lg * 4 + r);
        int orow = qt * 256 + w * 32 + lg * 4 + r;
        size_t base0 = (size_t)(b * N_ + orow) * C_ + h * 64 + lq;
        size_t base1 = base0 + (size_t)16 * C_;
#pragma unroll
        for (int ds = 0; ds < 4; ++ds) {
            attn_out[base0 + ds * 16] = f2bfc(o0[ds][r] * rl0);
            attn_out[base1 + ds * 16] = f2bfc(o1[ds][r] * rl1);
        }
    }
}

extern "C" void kernel_launch(void* const* d_in, const int* in_sizes, int n_in,
                              void* d_out, int out_size, void* d_ws, size_t ws_size,
                              hipStream_t stream) {
    const float* x      = (const float*)d_in[0];
    const float* qkv_w  = (const float*)d_in[1];
    const float* proj_w = (const float*)d_in[2];
    const float* proj_b = (const float*)d_in[3];
    float* out = (float*)d_out;

    ushort* ws    = (ushort*)d_ws;
    ushort* xb    = ws;                                   //  8192*1024
    ushort* wqkv  = xb + (size_t)8192 * 1024;             //  3072*1024
    ushort* wproj = wqkv + (size_t)3072 * 1024;           //  1024*1024
    ushort* qkb   = wproj + (size_t)1024 * 1024;          //  8192*2048
    ushort* vtb   = qkb + (size_t)8192 * 2048;            //  1024*8192
    ushort* attn  = vtb + (size_t)1024 * 8192;            //  8192*1024

    cvt_all<<<12288, 256, 0, stream>>>(x, qkv_w, proj_w, xb, wqkv, wproj);

    // Q,K: [token][2048] via proven 128^2 m97-structure (256^2 8-phase reverted:
    // at K=1024 it ran 687 TF vs 128^2's ~920 TF - wrong tool for this shape)
    gemm_bt<1><<<dim3(16, 64), 256, 0, stream>>>(xb, wqkv, (void*)qkb, nullptr, 8192, 2048, 1024);
    // V^T: [c][token]
    gemm_bt<1><<<dim3(64, 8), 256, 0, stream>>>(wqkv + (size_t)2048 * 1024, xb, (void*)vtb,
                                                nullptr, 1024, 8192, 1024);

    attn_fwd<<<dim3(4, 128), 512, 0, stream>>>(qkb, vtb, attn);

    gemm_bt<0><<<dim3(8, 64), 256, 0, stream>>>(attn, wproj, (void*)out, proj_b, 8192, 1024, 1024);
}

// Round 11
// 152.412 us; speedup vs baseline: 1.2960x; 1.2960x over previous
//
#include <hip/hip_runtime.h>
#include <hip/hip_bf16.h>
#include <stdint.h>

#define B_ 8
#define N_ 1024
#define C_ 1024
#define H_ 16

static constexpr float SCALE = 0.125f;            // 64^-0.5
static constexpr float LOG2E = 1.4426950408889634f;
static constexpr float SL    = SCALE * LOG2E;     // folded into Wq at cvt time

typedef __attribute__((ext_vector_type(4))) float f32x4;
typedef __attribute__((ext_vector_type(8))) short s16x8;

__device__ __forceinline__ ushort f2bf(float f) {
    union { float f; uint32_t u; } c; c.f = f;
    uint32_t u = c.u;
    return (ushort)((u + 0x7fffu + ((u >> 16) & 1u)) >> 16);
}

// compiler-friendly cast: hipcc fuses pairs into v_cvt_pk_bf16_f32 (m240)
__device__ __forceinline__ ushort f2bfc(float f) {
    union { __hip_bfloat16 h; ushort u; } c;
    c.h = __float2bfloat16(f);
    return c.u;
}

__device__ __forceinline__ void gload_lds16(const void* g, void* l) {
    __builtin_amdgcn_global_load_lds(
        (const __attribute__((address_space(1))) void*)g,
        (__attribute__((address_space(3))) void*)l,
        16, 0, 0);
}
__device__ __forceinline__ void gload_lds4(const void* g, void* l) {
    __builtin_amdgcn_global_load_lds(
        (const __attribute__((address_space(1))) void*)g,
        (__attribute__((address_space(3))) void*)l,
        4, 0, 0);
}

// ---------------- fused fp32 -> bf16 conversion for all three inputs ----------------
__global__ __launch_bounds__(256) void cvt_all(const float* __restrict__ x,
                                               const float* __restrict__ qkv_w,
                                               const float* __restrict__ proj_w,
                                               ushort* __restrict__ xb,
                                               ushort* __restrict__ wqkv,
                                               ushort* __restrict__ wproj) {
    int i = blockIdx.x * 256 + threadIdx.x;
    const float* src;
    ushort* dst;
    float sc = 1.0f;
    if (i < 2097152) {
        src = x; dst = xb;
    } else if (i < 2097152 + 786432) {
        i -= 2097152;
        src = qkv_w; dst = wqkv;
        if (i < 262144) sc = SL;
    } else {
        i -= 2097152 + 786432;
        src = proj_w; dst = wproj;
    }
    float4 v = ((const float4*)src)[i];
    ushort4 o = make_ushort4(f2bf(v.x * sc), f2bf(v.y * sc), f2bf(v.z * sc), f2bf(v.w * sc));
    ((ushort4*)dst)[i] = o;
}

// ---------------- 128x128 m97-structure GEMM: C = A * B^T ----------------
template<int OUT_BF16>
__global__ __launch_bounds__(256) void gemm_bt(const ushort* __restrict__ A,
                                               const ushort* __restrict__ Bw,
                                               void* __restrict__ Cout,
                                               const float* __restrict__ bias,
                                               int M, int Nout, int K) {
    __shared__ ushort Asm[128 * 64];
    __shared__ ushort Bsm[128 * 64];
    const int t = threadIdx.x;
    const int l = t & 63, w = t >> 6;
    const int lq = l & 15, lg = l >> 4;
    const int trow = blockIdx.y * 128, tcol = blockIdx.x * 128;
    const int wrow = (w >> 1) * 64, wcol = (w & 1) * 64;

    f32x4 acc[4][4] = {};

    const int srow0 = t >> 3;
    const int sc8 = (((t & 7) ^ (srow0 & 7)) * 8);
    const size_t abase = (size_t)(trow + srow0) * K + sc8;
    const size_t bbase = (size_t)(tcol + srow0) * K + sc8;

    for (int k0 = 0; k0 < K; k0 += 64) {
#pragma unroll
        for (int i = 0; i < 4; ++i) {
            gload_lds16(A + abase + (size_t)i * 32 * K + k0, &Asm[(i * 256 + w * 64) * 8]);
            gload_lds16(Bw + bbase + (size_t)i * 32 * K + k0, &Bsm[(i * 256 + w * 64) * 8]);
        }
        __syncthreads();
#pragma unroll
        for (int kk = 0; kk < 2; ++kk) {
            s16x8 af[4], bf[4];
#pragma unroll
            for (int m = 0; m < 4; ++m) {
                int row = wrow + m * 16 + lq;
                int ch = (kk * 4 + lg) ^ (row & 7);
                af[m] = *(const s16x8*)&Asm[row * 64 + ch * 8];
            }
#pragma unroll
            for (int n = 0; n < 4; ++n) {
                int row = wcol + n * 16 + lq;
                int ch = (kk * 4 + lg) ^ (row & 7);
                bf[n] = *(const s16x8*)&Bsm[row * 64 + ch * 8];
            }
#pragma unroll
            for (int m = 0; m < 4; ++m)
#pragma unroll
                for (int n = 0; n < 4; ++n)
                    acc[m][n] = __builtin_amdgcn_mfma_f32_16x16x32_bf16(af[m], bf[n], acc[m][n], 0, 0, 0);
        }
        __syncthreads();
    }

#pragma unroll
    for (int m = 0; m < 4; ++m)
#pragma unroll
        for (int n = 0; n < 4; ++n)
#pragma unroll
            for (int r = 0; r < 4; ++r) {
                int row = trow + wrow + m * 16 + lg * 4 + r;
                int col = tcol + wcol + n * 16 + lq;
                if (OUT_BF16) {
                    ((ushort*)Cout)[(size_t)row * Nout + col] = f2bfc(acc[m][n][r]);
                } else {
                    ((float*)Cout)[(size_t)row * Nout + col] = acc[m][n][r] + bias[col];
                }
            }
}

// ---------------- fused flash attention (r9 structure: QBLK=256, KVBLK=64) ----------------
// 8 waves x 32 q-rows (two 16-row subtiles/wave): each K-frag and V-frag ds_read feeds
// TWO MFMAs. grid 512 blocks (2/CU). KVBLK=64 single-buffer (KVBLK=128 spilled: score
// regs exceeded the launch_bounds(512,4) 128-VGPR budget -> 159MB scratch traffic, r10).
// K: one gload_lds16/thread, [64][64] 16B-chunk XOR swizzle. V: 4 gload_lds4/thread,
// key-permutation + bank-swizzle folded into per-lane SOURCE addresses.
// Swapped QK^T: lane owns 16 scores per q-subtile of query q=l&15; unnormalized
// softmax (Q pre-scaled by SL; exp2 direct); l_run reduced once at epilogue.
__global__ __launch_bounds__(512, 4) void attn_fwd(const ushort* __restrict__ qk,
                                                   const ushort* __restrict__ vt,
                                                   ushort* __restrict__ attn_out) {
    __shared__ ushort Klds[64 * 64];
    __shared__ ushort Vlds[64 * 64];

    const int t = threadIdx.x, l = t & 63, w = t >> 6;
    const int lq = l & 15, lg = l >> 4;

    // XCD swizzle over 512 blocks: 64 logical/XCD = 16 bh x 4 q-tiles (qt fastest)
    const int serial = blockIdx.x + 4 * blockIdx.y;
    const int logical = (serial & 7) * 64 + (serial >> 3);
    const int qt = logical & 3;
    const int bh = logical >> 2;
    const int b = bh >> 4, h = bh & 15;

    // two q-subtiles per wave: rows qbase and qbase+16
    const int qbase = qt * 256 + w * 32 + lq;
    const size_t qoff0 = (size_t)(b * N_ + qbase) * 2048 + h * 64;
    const size_t qoff1 = qoff0 + (size_t)16 * 2048;
    const s16x8 qa0 = *(const s16x8*)&qk[qoff0 + lg * 8];
    const s16x8 qa1 = *(const s16x8*)&qk[qoff0 + 32 + lg * 8];
    const s16x8 qb0 = *(const s16x8*)&qk[qoff1 + lg * 8];
    const s16x8 qb1 = *(const s16x8*)&qk[qoff1 + 32 + lg * 8];

    float lr0 = 0.f, lr1 = 0.f;
    f32x4 o0[4] = {}, o1[4] = {};

    // K staging (t-indexed)
    const int srow0 = t >> 3;
    const int sc8 = ((t & 7) ^ (srow0 & 7)) * 8;
    const size_t kgbase = (size_t)(b * N_ + srow0) * 2048 + 1024 + h * 64 + sc8;

    // V staging (t-indexed)
    const ushort* vptr[4];
#pragma unroll
    for (int j = 0; j < 4; ++j) {
        const int d = 8 * w + 2 * j + (l >> 5);
        const int c = ((l & 31) >> 2) ^ (d & 7);
        const int s = c * 8 + (l & 3) * 2;
        const int key = (s >> 5) * 32 + ((s >> 2) & 1) * 16 + ((s >> 3) & 3) * 4 + (s & 3);
        vptr[j] = vt + (size_t)(h * 64 + d) * (B_ * N_) + b * N_ + key;
    }

    for (int kt = 0; kt < N_ / 64; ++kt) {
        gload_lds16(qk + kgbase + (size_t)kt * 64 * 2048, &Klds[w * 512]);
#pragma unroll
        for (int j = 0; j < 4; ++j)
            gload_lds4(vptr[j] + kt * 64, &Vlds[w * 512 + j * 128]);
        __syncthreads();

        f32x4 s0[4], s1[4];
#pragma unroll
        for (int g = 0; g < 4; ++g) {
            int key = g * 16 + lq;
            const s16x8 kf0 = *(const s16x8*)&Klds[key * 64 + ((lg ^ (key & 7)) * 8)];
            const s16x8 kf1 = *(const s16x8*)&Klds[key * 64 + (((4 + lg) ^ (key & 7)) * 8)];
            f32x4 z0 = {}, z1 = {};
            z0    = __builtin_amdgcn_mfma_f32_16x16x32_bf16(kf0, qa0, z0, 0, 0, 0);
            s0[g] = __builtin_amdgcn_mfma_f32_16x16x32_bf16(kf1, qa1, z0, 0, 0, 0);
            z1    = __builtin_amdgcn_mfma_f32_16x16x32_bf16(kf0, qb0, z1, 0, 0, 0);
            s1[g] = __builtin_amdgcn_mfma_f32_16x16x32_bf16(kf1, qb1, z1, 0, 0, 0);
        }

        // exp2 + pack fused per kb (caps live registers); V-frag read once, two MFMAs
#pragma unroll
        for (int kb = 0; kb < 2; ++kb) {
            s16x8 pf0, pf1;
#pragma unroll
            for (int i = 0; i < 4; ++i) {
                float a0 = __builtin_amdgcn_exp2f(s0[2 * kb][i]);
                float a1 = __builtin_amdgcn_exp2f(s0[2 * kb + 1][i]);
                float b0 = __builtin_amdgcn_exp2f(s1[2 * kb][i]);
                float b1 = __builtin_amdgcn_exp2f(s1[2 * kb + 1][i]);
                lr0 += a0 + a1;
                lr1 += b0 + b1;
                pf0[i] = (short)f2bfc(a0); pf0[4 + i] = (short)f2bfc(a1);
                pf1[i] = (short)f2bfc(b0); pf1[4 + i] = (short)f2bfc(b1);
            }
#pragma unroll
            for (int ds = 0; ds < 4; ++ds) {
                const s16x8 vf = *(const s16x8*)
                    &Vlds[(ds * 16 + lq) * 64 + (((kb * 4 + lg) ^ (lq & 7)) * 8)];
                o0[ds] = __builtin_amdgcn_mfma_f32_16x16x32_bf16(pf0, vf, o0[ds], 0, 0, 0);
                o1[ds] = __builtin_amdgcn_mfma_f32_16x16x32_bf16(pf1, vf, o1[ds], 0, 0, 0);
            }
        }
        __syncthreads();
    }

    lr0 += __shfl_xor(lr0, 16); lr0 += __shfl_xor(lr0, 32);
    lr1 += __shfl_xor(lr1, 16); lr1 += __shfl_xor(lr1, 32);

#pragma unroll
    for (int r = 0; r < 4; ++r) {
        float rl0 = 1.f / __shfl(lr0, lg * 4 + r);
        float rl1 = 1.f / __shfl(lr1, lg * 4 + r);
        int orow = qt * 256 + w * 32 + lg * 4 + r;
        size_t base0 = (size_t)(b * N_ + orow) * C_ + h * 64 + lq;
        size_t base1 = base0 + (size_t)16 * C_;
#pragma unroll
        for (int ds = 0; ds < 4; ++ds) {
            attn_out[base0 + ds * 16] = f2bfc(o0[ds][r] * rl0);
            attn_out[base1 + ds * 16] = f2bfc(o1[ds][r] * rl1);
        }
    }
}

extern "C" void kernel_launch(void* const* d_in, const int* in_sizes, int n_in,
                              void* d_out, int out_size, void* d_ws, size_t ws_size,
                              hipStream_t stream) {
    const float* x      = (const float*)d_in[0];
    const float* qkv_w  = (const float*)d_in[1];
    const float* proj_w = (const float*)d_in[2];
    const float* proj_b = (const float*)d_in[3];
    float* out = (float*)d_out;

    ushort* ws    = (ushort*)d_ws;
    ushort* xb    = ws;                                   //  8192*1024
    ushort* wqkv  = xb + (size_t)8192 * 1024;             //  3072*1024
    ushort* wproj = wqkv + (size_t)3072 * 1024;           //  1024*1024
    ushort* qkb   = wproj + (size_t)1024 * 1024;          //  8192*2048
    ushort* vtb   = qkb + (size_t)8192 * 2048;            //  1024*8192
    ushort* attn  = vtb + (size_t)1024 * 8192;            //  8192*1024

    cvt_all<<<12288, 256, 0, stream>>>(x, qkv_w, proj_w, xb, wqkv, wproj);

    // Q,K: [token][2048] via proven 128^2 m97-structure
    gemm_bt<1><<<dim3(16, 64), 256, 0, stream>>>(xb, wqkv, (void*)qkb, nullptr, 8192, 2048, 1024);
    // V^T: [c][token]
    gemm_bt<1><<<dim3(64, 8), 256, 0, stream>>>(wqkv + (size_t)2048 * 1024, xb, (void*)vtb,
                                                nullptr, 1024, 8192, 1024);

    attn_fwd<<<dim3(4, 128), 512, 0, stream>>>(qkb, vtb, attn);

    gemm_bt<0><<<dim3(8, 64), 256, 0, stream>>>(attn, wproj, (void*)out, proj_b, 8192, 1024, 1024);
}

// Round 12
// 145.920 us; speedup vs baseline: 1.3537x; 1.0445x over previous
//
#include <hip/hip_runtime.h>
#include <hip/hip_bf16.h>
#include <stdint.h>

#define B_ 8
#define N_ 1024
#define C_ 1024
#define H_ 16

static constexpr float SCALE = 0.125f;            // 64^-0.5
static constexpr float LOG2E = 1.4426950408889634f;
static constexpr float SL    = SCALE * LOG2E;     // folded into Wq at cvt time

typedef __attribute__((ext_vector_type(4))) float f32x4;
typedef __attribute__((ext_vector_type(8))) short s16x8;

__device__ __forceinline__ ushort f2bf(float f) {
    union { float f; uint32_t u; } c; c.f = f;
    uint32_t u = c.u;
    return (ushort)((u + 0x7fffu + ((u >> 16) & 1u)) >> 16);
}

// compiler-friendly cast: hipcc fuses pairs into v_cvt_pk_bf16_f32 (m240)
__device__ __forceinline__ ushort f2bfc(float f) {
    union { __hip_bfloat16 h; ushort u; } c;
    c.h = __float2bfloat16(f);
    return c.u;
}

__device__ __forceinline__ void gload_lds16(const void* g, void* l) {
    __builtin_amdgcn_global_load_lds(
        (const __attribute__((address_space(1))) void*)g,
        (__attribute__((address_space(3))) void*)l,
        16, 0, 0);
}
__device__ __forceinline__ void gload_lds4(const void* g, void* l) {
    __builtin_amdgcn_global_load_lds(
        (const __attribute__((address_space(1))) void*)g,
        (__attribute__((address_space(3))) void*)l,
        4, 0, 0);
}

// ---------------- fused fp32 -> bf16 conversion for all three inputs ----------------
__global__ __launch_bounds__(256) void cvt_all(const float* __restrict__ x,
                                               const float* __restrict__ qkv_w,
                                               const float* __restrict__ proj_w,
                                               ushort* __restrict__ xb,
                                               ushort* __restrict__ wqkv,
                                               ushort* __restrict__ wproj) {
    int i = blockIdx.x * 256 + threadIdx.x;
    const float* src;
    ushort* dst;
    float sc = 1.0f;
    if (i < 2097152) {
        src = x; dst = xb;
    } else if (i < 2097152 + 786432) {
        i -= 2097152;
        src = qkv_w; dst = wqkv;
        if (i < 262144) sc = SL;
    } else {
        i -= 2097152 + 786432;
        src = proj_w; dst = wproj;
    }
    float4 v = ((const float4*)src)[i];
    ushort4 o = make_ushort4(f2bf(v.x * sc), f2bf(v.y * sc), f2bf(v.z * sc), f2bf(v.w * sc));
    ((ushort4*)dst)[i] = o;
}

// ---------------- 128x128 m97-structure GEMM: C = A * B^T (+T1 XCD swizzle) ----------------
template<int OUT_BF16>
__global__ __launch_bounds__(256) void gemm_bt(const ushort* __restrict__ A,
                                               const ushort* __restrict__ Bw,
                                               void* __restrict__ Cout,
                                               const float* __restrict__ bias,
                                               int M, int Nout, int K) {
    __shared__ ushort Asm[128 * 64];
    __shared__ ushort Bsm[128 * 64];
    const int t = threadIdx.x;
    const int l = t & 63, w = t >> 6;
    const int lq = l & 15, lg = l >> 4;

    // bijective XCD swizzle (all grids here have nwg % 8 == 0)
    int bid = blockIdx.y * gridDim.x + blockIdx.x;
    const int cpx = (gridDim.x * gridDim.y) >> 3;
    bid = (bid & 7) * cpx + (bid >> 3);
    const int trow = (bid / gridDim.x) * 128, tcol = (bid % gridDim.x) * 128;

    const int wrow = (w >> 1) * 64, wcol = (w & 1) * 64;

    f32x4 acc[4][4] = {};

    const int srow0 = t >> 3;
    const int sc8 = (((t & 7) ^ (srow0 & 7)) * 8);
    const size_t abase = (size_t)(trow + srow0) * K + sc8;
    const size_t bbase = (size_t)(tcol + srow0) * K + sc8;

    for (int k0 = 0; k0 < K; k0 += 64) {
#pragma unroll
        for (int i = 0; i < 4; ++i) {
            gload_lds16(A + abase + (size_t)i * 32 * K + k0, &Asm[(i * 256 + w * 64) * 8]);
            gload_lds16(Bw + bbase + (size_t)i * 32 * K + k0, &Bsm[(i * 256 + w * 64) * 8]);
        }
        __syncthreads();
#pragma unroll
        for (int kk = 0; kk < 2; ++kk) {
            s16x8 af[4], bf[4];
#pragma unroll
            for (int m = 0; m < 4; ++m) {
                int row = wrow + m * 16 + lq;
                int ch = (kk * 4 + lg) ^ (row & 7);
                af[m] = *(const s16x8*)&Asm[row * 64 + ch * 8];
            }
#pragma unroll
            for (int n = 0; n < 4; ++n) {
                int row = wcol + n * 16 + lq;
                int ch = (kk * 4 + lg) ^ (row & 7);
                bf[n] = *(const s16x8*)&Bsm[row * 64 + ch * 8];
            }
#pragma unroll
            for (int m = 0; m < 4; ++m)
#pragma unroll
                for (int n = 0; n < 4; ++n)
                    acc[m][n] = __builtin_amdgcn_mfma_f32_16x16x32_bf16(af[m], bf[n], acc[m][n], 0, 0, 0);
        }
        __syncthreads();
    }

#pragma unroll
    for (int m = 0; m < 4; ++m)
#pragma unroll
        for (int n = 0; n < 4; ++n)
#pragma unroll
            for (int r = 0; r < 4; ++r) {
                int row = trow + wrow + m * 16 + lg * 4 + r;
                int col = tcol + wcol + n * 16 + lq;
                if (OUT_BF16) {
                    ((ushort*)Cout)[(size_t)row * Nout + col] = f2bfc(acc[m][n][r]);
                } else {
                    ((float*)Cout)[(size_t)row * Nout + col] = acc[m][n][r] + bias[col];
                }
            }
}

// ---------------- 256x256 dbuf GEMM v2: ONE barrier per K-tile ----------------
// 512 thr = 8 waves (2M x 4N), per-wave out 128x64. BK=64. LDS 128 KB = 2 full-tile dbuf.
// Correctness needs only the tile-end vmcnt(0)+barrier: within a tile all LDS accesses to
// buf[cur] are reads; STAGE DMAs write only buf[nxt]; the kt+1 STAGE overwriting buffer kt
// is fenced by that barrier. All other barriers (r9's 10/tile) were scheduling-only and
// serialized LOAD phases against MFMA phases (MfmaUtil 25/VALUBusy 13). Compiler-inserted
// lgkmcnt orders ds_read->MFMA; setprio(T5) arbitrates desynced waves.
__global__ __launch_bounds__(512, 2) void gemm_bt256(const ushort* __restrict__ A,
                                                     const ushort* __restrict__ Bw,
                                                     ushort* __restrict__ Cout,
                                                     int M, int Nout, int K) {
    __shared__ ushort Asm[2][256 * 64];
    __shared__ ushort Bsm[2][256 * 64];
    const int t = threadIdx.x;
    const int l = t & 63, w = t >> 6;
    const int lq = l & 15, lg = l >> 4;
    const int wm = w >> 2, wn = w & 3;

    int bid = blockIdx.y * gridDim.x + blockIdx.x;
    const int cpx = (gridDim.x * gridDim.y) >> 3;
    bid = (bid & 7) * cpx + (bid >> 3);
    const int bx = bid % gridDim.x, by = bid / gridDim.x;
    const int trow = by * 256, tcol = bx * 256;

    f32x4 acc[8][4] = {};

    const int srow = t >> 3;
    const int scc = ((t & 7) ^ (srow & 7)) * 8;
    const size_t abase = (size_t)(trow + srow) * K + scc;
    const size_t bbase = (size_t)(tcol + srow) * K + scc;

#define STAGE256(buf, k0)                                                      \
    {                                                                          \
        _Pragma("unroll")                                                      \
        for (int j = 0; j < 4; ++j) {                                          \
            gload_lds16(A + abase + (size_t)j * 64 * K + (k0),                 \
                        &Asm[buf][(j * 512 + t) * 8]);                         \
            gload_lds16(Bw + bbase + (size_t)j * 64 * K + (k0),                \
                        &Bsm[buf][(j * 512 + t) * 8]);                         \
        }                                                                      \
    }
#define LOAD_A256(qr)                                                          \
    _Pragma("unroll") for (int m = 0; m < 4; ++m) {                            \
        const int row = wm * 128 + (qr) * 64 + m * 16 + lq;                    \
        _Pragma("unroll") for (int kk = 0; kk < 2; ++kk)                       \
            af[m][kk] = *(const s16x8*)&Asm[cur][row * 64 +                    \
                            (((kk * 4 + lg) ^ (row & 7)) * 8)];                \
    }
#define LOAD_B256(qc)                                                          \
    _Pragma("unroll") for (int n = 0; n < 2; ++n) {                            \
        const int row = wn * 64 + (qc) * 32 + n * 16 + lq;                     \
        _Pragma("unroll") for (int kk = 0; kk < 2; ++kk)                       \
            bf[n][kk] = *(const s16x8*)&Bsm[cur][row * 64 +                    \
                            (((kk * 4 + lg) ^ (row & 7)) * 8)];                \
    }
#define MFMA_Q256(qr, qc)                                                      \
    __builtin_amdgcn_s_setprio(1);                                             \
    _Pragma("unroll") for (int m = 0; m < 4; ++m)                              \
        _Pragma("unroll") for (int n = 0; n < 2; ++n)                          \
            _Pragma("unroll") for (int kk = 0; kk < 2; ++kk)                   \
                acc[(qr) * 4 + m][(qc) * 2 + n] =                              \
                    __builtin_amdgcn_mfma_f32_16x16x32_bf16(                   \
                        af[m][kk], bf[n][kk], acc[(qr) * 4 + m][(qc) * 2 + n], \
                        0, 0, 0);                                              \
    __builtin_amdgcn_s_setprio(0);

    STAGE256(0, 0);
    asm volatile("s_waitcnt vmcnt(0)" ::: "memory");
    __builtin_amdgcn_s_barrier();

    const int NT = K / 64;
    for (int kt = 0; kt < NT; ++kt) {
        const int cur = kt & 1, nxt = cur ^ 1;
        s16x8 af[4][2], bf[2][2];
        // issue next-tile staging first (latency hides under this tile's compute)
        if (kt < NT - 1) STAGE256(nxt, (kt + 1) * 64);
        LOAD_A256(0); LOAD_B256(0);
        MFMA_Q256(0, 0);
        LOAD_B256(1);
        MFMA_Q256(0, 1);
        LOAD_A256(1);
        MFMA_Q256(1, 1);
        LOAD_B256(0);
        MFMA_Q256(1, 0);
        // tile end: drain own DMAs, then release buffers to all waves
        asm volatile("s_waitcnt vmcnt(0)" ::: "memory");
        __builtin_amdgcn_s_barrier();
    }

#pragma unroll
    for (int mt = 0; mt < 8; ++mt)
#pragma unroll
        for (int nt = 0; nt < 4; ++nt)
#pragma unroll
            for (int r = 0; r < 4; ++r) {
                int row = trow + wm * 128 + mt * 16 + lg * 4 + r;
                int col = tcol + wn * 64 + nt * 16 + lq;
                Cout[(size_t)row * Nout + col] = f2bfc(acc[mt][nt][r]);
            }
#undef STAGE256
#undef LOAD_A256
#undef LOAD_B256
#undef MFMA_Q256
}

// ---------------- fused flash attention (QBLK=256, KVBLK=64) ----------------
__global__ __launch_bounds__(512, 4) void attn_fwd(const ushort* __restrict__ qk,
                                                   const ushort* __restrict__ vt,
                                                   ushort* __restrict__ attn_out) {
    __shared__ ushort Klds[64 * 64];
    __shared__ ushort Vlds[64 * 64];

    const int t = threadIdx.x, l = t & 63, w = t >> 6;
    const int lq = l & 15, lg = l >> 4;

    const int serial = blockIdx.x + 4 * blockIdx.y;
    const int logical = (serial & 7) * 64 + (serial >> 3);
    const int qt = logical & 3;
    const int bh = logical >> 2;
    const int b = bh >> 4, h = bh & 15;

    const int qbase = qt * 256 + w * 32 + lq;
    const size_t qoff0 = (size_t)(b * N_ + qbase) * 2048 + h * 64;
    const size_t qoff1 = qoff0 + (size_t)16 * 2048;
    const s16x8 qa0 = *(const s16x8*)&qk[qoff0 + lg * 8];
    const s16x8 qa1 = *(const s16x8*)&qk[qoff0 + 32 + lg * 8];
    const s16x8 qb0 = *(const s16x8*)&qk[qoff1 + lg * 8];
    const s16x8 qb1 = *(const s16x8*)&qk[qoff1 + 32 + lg * 8];

    float lr0 = 0.f, lr1 = 0.f;
    f32x4 o0[4] = {}, o1[4] = {};

    const int srow0 = t >> 3;
    const int sc8 = ((t & 7) ^ (srow0 & 7)) * 8;
    const size_t kgbase = (size_t)(b * N_ + srow0) * 2048 + 1024 + h * 64 + sc8;

    const ushort* vptr[4];
#pragma unroll
    for (int j = 0; j < 4; ++j) {
        const int d = 8 * w + 2 * j + (l >> 5);
        const int c = ((l & 31) >> 2) ^ (d & 7);
        const int s = c * 8 + (l & 3) * 2;
        const int key = (s >> 5) * 32 + ((s >> 2) & 1) * 16 + ((s >> 3) & 3) * 4 + (s & 3);
        vptr[j] = vt + (size_t)(h * 64 + d) * (B_ * N_) + b * N_ + key;
    }

    for (int kt = 0; kt < N_ / 64; ++kt) {
        gload_lds16(qk + kgbase + (size_t)kt * 64 * 2048, &Klds[w * 512]);
#pragma unroll
        for (int j = 0; j < 4; ++j)
            gload_lds4(vptr[j] + kt * 64, &Vlds[w * 512 + j * 128]);
        __syncthreads();

        f32x4 s0[4], s1[4];
#pragma unroll
        for (int g = 0; g < 4; ++g) {
            int key = g * 16 + lq;
            const s16x8 kf0 = *(const s16x8*)&Klds[key * 64 + ((lg ^ (key & 7)) * 8)];
            const s16x8 kf1 = *(const s16x8*)&Klds[key * 64 + (((4 + lg) ^ (key & 7)) * 8)];
            f32x4 z0 = {}, z1 = {};
            z0    = __builtin_amdgcn_mfma_f32_16x16x32_bf16(kf0, qa0, z0, 0, 0, 0);
            s0[g] = __builtin_amdgcn_mfma_f32_16x16x32_bf16(kf1, qa1, z0, 0, 0, 0);
            z1    = __builtin_amdgcn_mfma_f32_16x16x32_bf16(kf0, qb0, z1, 0, 0, 0);
            s1[g] = __builtin_amdgcn_mfma_f32_16x16x32_bf16(kf1, qb1, z1, 0, 0, 0);
        }

#pragma unroll
        for (int kb = 0; kb < 2; ++kb) {
            s16x8 pf0, pf1;
#pragma unroll
            for (int i = 0; i < 4; ++i) {
                float a0 = __builtin_amdgcn_exp2f(s0[2 * kb][i]);
                float a1 = __builtin_amdgcn_exp2f(s0[2 * kb + 1][i]);
                float b0 = __builtin_amdgcn_exp2f(s1[2 * kb][i]);
                float b1 = __builtin_amdgcn_exp2f(s1[2 * kb + 1][i]);
                lr0 += a0 + a1;
                lr1 += b0 + b1;
                pf0[i] = (short)f2bfc(a0); pf0[4 + i] = (short)f2bfc(a1);
                pf1[i] = (short)f2bfc(b0); pf1[4 + i] = (short)f2bfc(b1);
            }
#pragma unroll
            for (int ds = 0; ds < 4; ++ds) {
                const s16x8 vf = *(const s16x8*)
                    &Vlds[(ds * 16 + lq) * 64 + (((kb * 4 + lg) ^ (lq & 7)) * 8)];
                o0[ds] = __builtin_amdgcn_mfma_f32_16x16x32_bf16(pf0, vf, o0[ds], 0, 0, 0);
                o1[ds] = __builtin_amdgcn_mfma_f32_16x16x32_bf16(pf1, vf, o1[ds], 0, 0, 0);
            }
        }
        __syncthreads();
    }

    lr0 += __shfl_xor(lr0, 16); lr0 += __shfl_xor(lr0, 32);
    lr1 += __shfl_xor(lr1, 16); lr1 += __shfl_xor(lr1, 32);

#pragma unroll
    for (int r = 0; r < 4; ++r) {
        float rl0 = 1.f / __shfl(lr0, lg * 4 + r);
        float rl1 = 1.f / __shfl(lr1, lg * 4 + r);
        int orow = qt * 256 + w * 32 + lg * 4 + r;
        size_t base0 = (size_t)(b * N_ + orow) * C_ + h * 64 + lq;
        size_t base1 = base0 + (size_t)16 * C_;
#pragma unroll
        for (int ds = 0; ds < 4; ++ds) {
            attn_out[base0 + ds * 16] = f2bfc(o0[ds][r] * rl0);
            attn_out[base1 + ds * 16] = f2bfc(o1[ds][r] * rl1);
        }
    }
}

extern "C" void kernel_launch(void* const* d_in, const int* in_sizes, int n_in,
                              void* d_out, int out_size, void* d_ws, size_t ws_size,
                              hipStream_t stream) {
    const float* x      = (const float*)d_in[0];
    const float* qkv_w  = (const float*)d_in[1];
    const float* proj_w = (const float*)d_in[2];
    const float* proj_b = (const float*)d_in[3];
    float* out = (float*)d_out;

    ushort* ws    = (ushort*)d_ws;
    ushort* xb    = ws;                                   //  8192*1024
    ushort* wqkv  = xb + (size_t)8192 * 1024;             //  3072*1024
    ushort* wproj = wqkv + (size_t)3072 * 1024;           //  1024*1024
    ushort* qkb   = wproj + (size_t)1024 * 1024;          //  8192*2048
    ushort* vtb   = qkb + (size_t)8192 * 2048;            //  1024*8192
    ushort* attn  = vtb + (size_t)1024 * 8192;            //  8192*1024

    cvt_all<<<12288, 256, 0, stream>>>(x, qkv_w, proj_w, xb, wqkv, wproj);

    // Q,K: [token][2048] via 256^2 dbuf v2 (1 barrier/tile). 128^2 measured 593 TF at
    // this K=1024 shape (r11); bt256 r9 already beat it at 687 TF.
    gemm_bt256<<<dim3(8, 32), 512, 0, stream>>>(xb, wqkv, qkb, 8192, 2048, 1024);
    // V^T: [c][token]
    gemm_bt<1><<<dim3(64, 8), 256, 0, stream>>>(wqkv + (size_t)2048 * 1024, xb, (void*)vtb,
                                                nullptr, 1024, 8192, 1024);

    attn_fwd<<<dim3(4, 128), 512, 0, stream>>>(qkb, vtb, attn);

    gemm_bt<0><<<dim3(8, 64), 256, 0, stream>>>(attn, wproj, (void*)out, proj_b, 8192, 1024, 1024);
}